// Round 14
// baseline (264.253 us; speedup 1.0000x reference)
//
#include <hip/hip_runtime.h>
#include <hip/hip_bf16.h>
#include <math.h>

#define NPTS 2048
#define BN   16384
#define KNN_K 32
typedef unsigned long long u64;
typedef float f32x4 __attribute__((ext_vector_type(4)));
#define INF64 0xFFFFFFFFFFFFFFFFull

__device__ __forceinline__ u64 umin64(u64 a, u64 b) { return a < b ? a : b; }

// ---------------- Kernel A: exact kNN via prune + bitonic sort ----------------
// 512 threads = 8 waves = 8 queries per block; 2048 blocks.
// 24 KB point stage amortized over 8 queries (was 4); surv trimmed to 64
// entries/wave (sort path only reads lanes < cnt <= 64) -> 28 KB LDS total.
// Target 4 blocks/CU = 32 waves/CU to hide DS latency (was ~9 waves/CU).
__global__ __launch_bounds__(512, 8) void knn_kernel(const float* __restrict__ pts,
                                                     int* __restrict__ knn) {
    __shared__ float px[NPTS], py[NPTS], pz[NPTS];   // 24 KB
    __shared__ u64 surv[8][64];                      // 4 KB
    const int b = blockIdx.x >> 8;                   // 256 blocks per batch
    const int qbase = (blockIdx.x & 255) << 3;       // 8 queries per block
    const float* pb = pts + (size_t)b * NPTS * 3;
    for (int i = threadIdx.x; i < NPTS; i += 512) {
        px[i] = pb[i * 3 + 0];
        py[i] = pb[i * 3 + 1];
        pz[i] = pb[i * 3 + 2];
    }
    __syncthreads();
    const int wave = threadIdx.x >> 6, lane = threadIdx.x & 63;
    const int q = qbase + wave;
    const float qx = px[q], qy = py[q], qz = pz[q];

    // exact reference-order distances (no FMA contraction, correctly-rounded sqrt)
    float d[32];
#pragma unroll
    for (int t = 0; t < 32; ++t) {
        int j = t * 64 + lane;
        float dx = __fsub_rn(qx, px[j]);
        float dy = __fsub_rn(qy, py[j]);
        float dz = __fsub_rn(qz, pz[j]);
        float d2 = __fadd_rn(__fadd_rn(__fmul_rn(dx, dx), __fmul_rn(dy, dy)),
                             __fmul_rn(dz, dz));
        d[t] = __fsqrt_rn(d2);
    }

    float lmin = d[0];
#pragma unroll
    for (int t = 1; t < 32; ++t) lmin = fminf(lmin, d[t]);

    // bitonic sort of 64 lane-minima
    float v = lmin;
#pragma unroll
    for (int k = 2; k <= 64; k <<= 1) {
#pragma unroll
        for (int j = k >> 1; j > 0; j >>= 1) {
            float o = __shfl_xor(v, j, 64);
            bool up = ((lane & k) == 0);
            bool low = ((lane & j) == 0);
            float mn = fminf(v, o), mx = fmaxf(v, o);
            v = (low == up) ? mn : mx;
        }
    }
    float Tpre = __shfl(v, 31, 64);   // >= 32nd-smallest global distance

    u64* sw = surv[wave];
    unsigned cnt = 0;
#pragma unroll
    for (int t = 0; t < 32; ++t) {
        bool sel = (d[t] <= Tpre);
        u64 m = __ballot(sel);
        if (sel) {
            u64 key = ((u64)__float_as_uint(d[t]) << 32) | (unsigned)(t * 64 + lane);
            unsigned pos = cnt + (unsigned)__popcll(m & ((1ull << lane) - 1ull));
            if (pos < 64) sw[pos] = key;
        }
        cnt += (unsigned)__popcll(m);
    }

    int* kout = knn + ((size_t)b * NPTS + q) * KNN_K;
    __asm__ volatile("s_waitcnt lgkmcnt(0)" ::: "memory");  // own-wave LDS W->R fence

    if (cnt <= 64) {
        u64 key = (lane < (int)cnt) ? sw[lane] : INF64;
#pragma unroll
        for (int k = 2; k <= 64; k <<= 1) {
#pragma unroll
            for (int j = k >> 1; j > 0; j >>= 1) {
                u64 o = __shfl_xor(key, j, 64);
                bool up = ((lane & k) == 0);
                bool low = ((lane & j) == 0);
                bool lt = key < o;
                u64 mn = lt ? key : o, mx = lt ? o : key;
                key = (low == up) ? mn : mx;
            }
        }
        if (lane < KNN_K) kout[lane] = (int)(unsigned)(key & 0xFFFFFFFFull);
    } else {
        // rare exact fallback (survivors > 64)
        unsigned fmask = 0xFFFFFFFFu;
        for (int r = 0; r < KNN_K; ++r) {
            u64 mm = INF64;
#pragma unroll
            for (int t = 0; t < 32; ++t) {
                u64 kk = ((u64)__float_as_uint(d[t]) << 32) | (unsigned)(t * 64 + lane);
                mm = umin64(mm, ((fmask >> t) & 1u) ? kk : INF64);
            }
#pragma unroll
            for (int s = 1; s < 64; s <<= 1) mm = umin64(mm, __shfl_xor(mm, s, 64));
            unsigned j = (unsigned)(mm & 0xFFFFFFFFull);
            if (lane == (int)(j & 63)) fmask &= ~(1u << (j >> 6));
            if (lane == 0) kout[r] = (int)j;
        }
    }
}

// ---------------- Kernel B: fused MLP (layers 1..3) -> f3 [BN][256] ----------------
// (unchanged from round 13: 1024 blocks, wave owns 4 points both phases,
//  own-wave lgkmcnt fence, Pp=4 halves issued W3 L2 traffic)
__global__ __launch_bounds__(256, 8) void mlp123_kernel(const float* __restrict__ pts,
        const float* __restrict__ W1, const float* __restrict__ b1,
        const float* __restrict__ W2, const float* __restrict__ b2,
        const float* __restrict__ W3, const float* __restrict__ b3,
        float* __restrict__ f3) {
    __shared__ float h2s[16][128];   // 8 KB
    const int tid = threadIdx.x;
    const int wv = tid >> 6, lane = tid & 63;
    const int p0 = blockIdx.x << 4;
    const int pbase = wv * 4;        // this wave's local points

    // ---- phase 0: layers 1+2 for this wave's 4 points ----
    {
        const float w1a = W1[lane], w1b = W1[64 + lane], w1c = W1[128 + lane];
        const float b1v = b1[lane];
        float h1v[4];
#pragma unroll
        for (int p = 0; p < 4; ++p) {
            const int pp = __builtin_amdgcn_readfirstlane(p0 + pbase + p);
            const float* ptp = pts + (size_t)pp * 3;
            h1v[p] = fmaxf(fmaf(ptp[0], w1a, fmaf(ptp[1], w1b, fmaf(ptp[2], w1c, b1v))), 0.f);
        }
        float2 b2v = *(const float2*)(b2 + 2 * lane);
        float a0[4], a1[4];
#pragma unroll
        for (int p = 0; p < 4; ++p) { a0[p] = b2v.x; a1[p] = b2v.y; }
#pragma unroll
        for (int i = 0; i < 64; ++i) {
            float2 w = *(const float2*)(W2 + i * 128 + 2 * lane);
#pragma unroll
            for (int p = 0; p < 4; ++p) {
                float h = __shfl(h1v[p], i, 64);
                a0[p] = fmaf(h, w.x, a0[p]);
                a1[p] = fmaf(h, w.y, a1[p]);
            }
        }
#pragma unroll
        for (int p = 0; p < 4; ++p)
            *(float2*)&h2s[pbase + p][2 * lane] =
                make_float2(fmaxf(a0[p], 0.f), fmaxf(a1[p], 0.f));
    }
    // own-wave LDS write->read fence (phase 1 reads only this wave's rows)
    __asm__ volatile("s_waitcnt lgkmcnt(0)" ::: "memory");

    // ---- phase 1: layer 3; lane -> channels c0..c0+3, points pbase..pbase+3 ----
    const int c0 = lane * 4;
    float4 acc0 = make_float4(0.f, 0.f, 0.f, 0.f);
    float4 acc1 = make_float4(0.f, 0.f, 0.f, 0.f);
    float4 acc2 = make_float4(0.f, 0.f, 0.f, 0.f);
    float4 acc3 = make_float4(0.f, 0.f, 0.f, 0.f);
    for (int k4 = 0; k4 < 32; ++k4) {
        float4 h0 = *(const float4*)&h2s[pbase + 0][k4 * 4];
        float4 h1 = *(const float4*)&h2s[pbase + 1][k4 * 4];
        float4 h2 = *(const float4*)&h2s[pbase + 2][k4 * 4];
        float4 h3 = *(const float4*)&h2s[pbase + 3][k4 * 4];
#pragma unroll
        for (int u = 0; u < 4; ++u) {
            float4 w = *(const float4*)(W3 + (size_t)(k4 * 4 + u) * 256 + c0);
            float e0 = (u == 0) ? h0.x : (u == 1) ? h0.y : (u == 2) ? h0.z : h0.w;
            float e1 = (u == 0) ? h1.x : (u == 1) ? h1.y : (u == 2) ? h1.z : h1.w;
            float e2 = (u == 0) ? h2.x : (u == 1) ? h2.y : (u == 2) ? h2.z : h2.w;
            float e3 = (u == 0) ? h3.x : (u == 1) ? h3.y : (u == 2) ? h3.z : h3.w;
            acc0.x = fmaf(e0, w.x, acc0.x); acc0.y = fmaf(e0, w.y, acc0.y);
            acc0.z = fmaf(e0, w.z, acc0.z); acc0.w = fmaf(e0, w.w, acc0.w);
            acc1.x = fmaf(e1, w.x, acc1.x); acc1.y = fmaf(e1, w.y, acc1.y);
            acc1.z = fmaf(e1, w.z, acc1.z); acc1.w = fmaf(e1, w.w, acc1.w);
            acc2.x = fmaf(e2, w.x, acc2.x); acc2.y = fmaf(e2, w.y, acc2.y);
            acc2.z = fmaf(e2, w.z, acc2.z); acc2.w = fmaf(e2, w.w, acc2.w);
            acc3.x = fmaf(e3, w.x, acc3.x); acc3.y = fmaf(e3, w.y, acc3.y);
            acc3.z = fmaf(e3, w.z, acc3.z); acc3.w = fmaf(e3, w.w, acc3.w);
        }
    }
    float4 bb = *(const float4*)(b3 + c0);
    float4 r0 = make_float4(fmaxf(acc0.x + bb.x, 0.f), fmaxf(acc0.y + bb.y, 0.f),
                            fmaxf(acc0.z + bb.z, 0.f), fmaxf(acc0.w + bb.w, 0.f));
    float4 r1 = make_float4(fmaxf(acc1.x + bb.x, 0.f), fmaxf(acc1.y + bb.y, 0.f),
                            fmaxf(acc1.z + bb.z, 0.f), fmaxf(acc1.w + bb.w, 0.f));
    float4 r2 = make_float4(fmaxf(acc2.x + bb.x, 0.f), fmaxf(acc2.y + bb.y, 0.f),
                            fmaxf(acc2.z + bb.z, 0.f), fmaxf(acc2.w + bb.w, 0.f));
    float4 r3 = make_float4(fmaxf(acc3.x + bb.x, 0.f), fmaxf(acc3.y + bb.y, 0.f),
                            fmaxf(acc3.z + bb.z, 0.f), fmaxf(acc3.w + bb.w, 0.f));
    float* ob = f3 + ((size_t)(p0 + pbase)) * 256 + c0;
    *(float4*)(ob)           = r0;
    *(float4*)(ob + 256)     = r1;
    *(float4*)(ob + 512)     = r2;
    *(float4*)(ob + 768)     = r3;
}

// ---------------- Kernel C: gather + mean; batch pinned to XCD via blockIdx&7 ----------------
__global__ __launch_bounds__(256) void gather_mean_kernel(const float* __restrict__ f3,
        const int* __restrict__ knn, float* __restrict__ out) {
    int wave = threadIdx.x >> 6, lane = threadIdx.x & 63;
    int b  = blockIdx.x & 7;
    int qg = blockIdx.x >> 3;          // 0..511
    int q  = b * NPTS + qg * 4 + wave;
    const int* kq = knn + (size_t)q * KNN_K;
    const float4* fb = (const float4*)(f3 + (size_t)b * NPTS * 256);
    float4 acc = make_float4(0.f, 0.f, 0.f, 0.f);
#pragma unroll
    for (int k = 0; k < KNN_K; ++k) {
        int j = kq[k];
        float4 v2 = fb[(size_t)j * 64 + lane];
        acc.x += v2.x; acc.y += v2.y; acc.z += v2.z; acc.w += v2.w;
    }
    f32x4 r;
    r.x = acc.x * 0.03125f; r.y = acc.y * 0.03125f;
    r.z = acc.z * 0.03125f; r.w = acc.w * 0.03125f;
    __builtin_nontemporal_store(r, (f32x4*)(out + (size_t)q * 256 + lane * 4));
}

extern "C" void kernel_launch(void* const* d_in, const int* in_sizes, int n_in,
                              void* d_out, int out_size, void* d_ws, size_t ws_size,
                              hipStream_t stream) {
    const float* pts = (const float*)d_in[0];
    const float* W1  = (const float*)d_in[1];
    const float* b1  = (const float*)d_in[2];
    const float* W2  = (const float*)d_in[3];
    const float* b2  = (const float*)d_in[4];
    const float* W3  = (const float*)d_in[5];
    const float* b3  = (const float*)d_in[6];
    float* out = (float*)d_out;
    char* ws = (char*)d_ws;
    int*   knn = (int*)ws;                               // 2 MB
    float* f3  = (float*)(ws + ((size_t)2 << 20));       // 16.8 MB

    hipLaunchKernelGGL(knn_kernel,         dim3(2048), dim3(512), 0, stream, pts, knn);
    hipLaunchKernelGGL(mlp123_kernel,      dim3(1024), dim3(256), 0, stream,
                       pts, W1, b1, W2, b2, W3, b3, f3);
    hipLaunchKernelGGL(gather_mean_kernel, dim3(4096), dim3(256), 0, stream, f3, knn, out);
}

// Round 15
// 170.609 us; speedup vs baseline: 1.5489x; 1.5489x over previous
//
#include <hip/hip_runtime.h>
#include <hip/hip_bf16.h>
#include <math.h>

#define NPTS 2048
#define BN   16384
#define KNN_K 32
typedef unsigned long long u64;
typedef float f32x4 __attribute__((ext_vector_type(4)));
#define INF64 0xFFFFFFFFFFFFFFFFull

__device__ __forceinline__ u64 umin64(u64 a, u64 b) { return a < b ? a : b; }

// ---------------- Kernel A: exact kNN via prune + bitonic sort ----------------
// 512 threads = 8 waves = 8 queries per block; 2048 blocks.
// __launch_bounds__(512, 4): VGPR cap 128. Round-14 lesson: (512,8) capped
// VGPR at 64, compiler chose 32 -> d[32] spilled to scratch (134 MB FETCH,
// 2.8x slower). This kernel needs >= ~48 VGPRs.
__global__ __launch_bounds__(512, 4) void knn_kernel(const float* __restrict__ pts,
                                                     int* __restrict__ knn) {
    __shared__ float px[NPTS], py[NPTS], pz[NPTS];   // 24 KB
    __shared__ u64 surv[8][64];                      // 4 KB
    const int b = blockIdx.x >> 8;                   // 256 blocks per batch
    const int qbase = (blockIdx.x & 255) << 3;       // 8 queries per block
    const float* pb = pts + (size_t)b * NPTS * 3;
    for (int i = threadIdx.x; i < NPTS; i += 512) {
        px[i] = pb[i * 3 + 0];
        py[i] = pb[i * 3 + 1];
        pz[i] = pb[i * 3 + 2];
    }
    __syncthreads();
    const int wave = threadIdx.x >> 6, lane = threadIdx.x & 63;
    const int q = qbase + wave;
    const float qx = px[q], qy = py[q], qz = pz[q];

    // exact reference-order distances (no FMA contraction, correctly-rounded sqrt)
    float d[32];
#pragma unroll
    for (int t = 0; t < 32; ++t) {
        int j = t * 64 + lane;
        float dx = __fsub_rn(qx, px[j]);
        float dy = __fsub_rn(qy, py[j]);
        float dz = __fsub_rn(qz, pz[j]);
        float d2 = __fadd_rn(__fadd_rn(__fmul_rn(dx, dx), __fmul_rn(dy, dy)),
                             __fmul_rn(dz, dz));
        d[t] = __fsqrt_rn(d2);
    }

    float lmin = d[0];
#pragma unroll
    for (int t = 1; t < 32; ++t) lmin = fminf(lmin, d[t]);

    // bitonic sort of 64 lane-minima
    float v = lmin;
#pragma unroll
    for (int k = 2; k <= 64; k <<= 1) {
#pragma unroll
        for (int j = k >> 1; j > 0; j >>= 1) {
            float o = __shfl_xor(v, j, 64);
            bool up = ((lane & k) == 0);
            bool low = ((lane & j) == 0);
            float mn = fminf(v, o), mx = fmaxf(v, o);
            v = (low == up) ? mn : mx;
        }
    }
    float Tpre = __shfl(v, 31, 64);   // >= 32nd-smallest global distance

    u64* sw = surv[wave];
    unsigned cnt = 0;
#pragma unroll
    for (int t = 0; t < 32; ++t) {
        bool sel = (d[t] <= Tpre);
        u64 m = __ballot(sel);
        if (sel) {
            u64 key = ((u64)__float_as_uint(d[t]) << 32) | (unsigned)(t * 64 + lane);
            unsigned pos = cnt + (unsigned)__popcll(m & ((1ull << lane) - 1ull));
            if (pos < 64) sw[pos] = key;
        }
        cnt += (unsigned)__popcll(m);
    }

    int* kout = knn + ((size_t)b * NPTS + q) * KNN_K;
    __asm__ volatile("s_waitcnt lgkmcnt(0)" ::: "memory");  // own-wave LDS W->R fence

    if (cnt <= 64) {
        u64 key = (lane < (int)cnt) ? sw[lane] : INF64;
#pragma unroll
        for (int k = 2; k <= 64; k <<= 1) {
#pragma unroll
            for (int j = k >> 1; j > 0; j >>= 1) {
                u64 o = __shfl_xor(key, j, 64);
                bool up = ((lane & k) == 0);
                bool low = ((lane & j) == 0);
                bool lt = key < o;
                u64 mn = lt ? key : o, mx = lt ? o : key;
                key = (low == up) ? mn : mx;
            }
        }
        if (lane < KNN_K) kout[lane] = (int)(unsigned)(key & 0xFFFFFFFFull);
    } else {
        // rare exact fallback (survivors > 64)
        unsigned fmask = 0xFFFFFFFFu;
        for (int r = 0; r < KNN_K; ++r) {
            u64 mm = INF64;
#pragma unroll
            for (int t = 0; t < 32; ++t) {
                u64 kk = ((u64)__float_as_uint(d[t]) << 32) | (unsigned)(t * 64 + lane);
                mm = umin64(mm, ((fmask >> t) & 1u) ? kk : INF64);
            }
#pragma unroll
            for (int s = 1; s < 64; s <<= 1) mm = umin64(mm, __shfl_xor(mm, s, 64));
            unsigned j = (unsigned)(mm & 0xFFFFFFFFull);
            if (lane == (int)(j & 63)) fmask &= ~(1u << (j >> 6));
            if (lane == 0) kout[r] = (int)j;
        }
    }
}

// ---------------- Kernel B: fused MLP (layers 1..3) -> f3 [BN][256] ----------------
// (unchanged from round 13: 1024 blocks, wave owns 4 points both phases,
//  own-wave lgkmcnt fence, Pp=4 halves issued W3 L2 traffic)
__global__ __launch_bounds__(256, 8) void mlp123_kernel(const float* __restrict__ pts,
        const float* __restrict__ W1, const float* __restrict__ b1,
        const float* __restrict__ W2, const float* __restrict__ b2,
        const float* __restrict__ W3, const float* __restrict__ b3,
        float* __restrict__ f3) {
    __shared__ float h2s[16][128];   // 8 KB
    const int tid = threadIdx.x;
    const int wv = tid >> 6, lane = tid & 63;
    const int p0 = blockIdx.x << 4;
    const int pbase = wv * 4;        // this wave's local points

    // ---- phase 0: layers 1+2 for this wave's 4 points ----
    {
        const float w1a = W1[lane], w1b = W1[64 + lane], w1c = W1[128 + lane];
        const float b1v = b1[lane];
        float h1v[4];
#pragma unroll
        for (int p = 0; p < 4; ++p) {
            const int pp = __builtin_amdgcn_readfirstlane(p0 + pbase + p);
            const float* ptp = pts + (size_t)pp * 3;
            h1v[p] = fmaxf(fmaf(ptp[0], w1a, fmaf(ptp[1], w1b, fmaf(ptp[2], w1c, b1v))), 0.f);
        }
        float2 b2v = *(const float2*)(b2 + 2 * lane);
        float a0[4], a1[4];
#pragma unroll
        for (int p = 0; p < 4; ++p) { a0[p] = b2v.x; a1[p] = b2v.y; }
#pragma unroll
        for (int i = 0; i < 64; ++i) {
            float2 w = *(const float2*)(W2 + i * 128 + 2 * lane);
#pragma unroll
            for (int p = 0; p < 4; ++p) {
                float h = __shfl(h1v[p], i, 64);
                a0[p] = fmaf(h, w.x, a0[p]);
                a1[p] = fmaf(h, w.y, a1[p]);
            }
        }
#pragma unroll
        for (int p = 0; p < 4; ++p)
            *(float2*)&h2s[pbase + p][2 * lane] =
                make_float2(fmaxf(a0[p], 0.f), fmaxf(a1[p], 0.f));
    }
    // own-wave LDS write->read fence (phase 1 reads only this wave's rows)
    __asm__ volatile("s_waitcnt lgkmcnt(0)" ::: "memory");

    // ---- phase 1: layer 3; lane -> channels c0..c0+3, points pbase..pbase+3 ----
    const int c0 = lane * 4;
    float4 acc0 = make_float4(0.f, 0.f, 0.f, 0.f);
    float4 acc1 = make_float4(0.f, 0.f, 0.f, 0.f);
    float4 acc2 = make_float4(0.f, 0.f, 0.f, 0.f);
    float4 acc3 = make_float4(0.f, 0.f, 0.f, 0.f);
    for (int k4 = 0; k4 < 32; ++k4) {
        float4 h0 = *(const float4*)&h2s[pbase + 0][k4 * 4];
        float4 h1 = *(const float4*)&h2s[pbase + 1][k4 * 4];
        float4 h2 = *(const float4*)&h2s[pbase + 2][k4 * 4];
        float4 h3 = *(const float4*)&h2s[pbase + 3][k4 * 4];
#pragma unroll
        for (int u = 0; u < 4; ++u) {
            float4 w = *(const float4*)(W3 + (size_t)(k4 * 4 + u) * 256 + c0);
            float e0 = (u == 0) ? h0.x : (u == 1) ? h0.y : (u == 2) ? h0.z : h0.w;
            float e1 = (u == 0) ? h1.x : (u == 1) ? h1.y : (u == 2) ? h1.z : h1.w;
            float e2 = (u == 0) ? h2.x : (u == 1) ? h2.y : (u == 2) ? h2.z : h2.w;
            float e3 = (u == 0) ? h3.x : (u == 1) ? h3.y : (u == 2) ? h3.z : h3.w;
            acc0.x = fmaf(e0, w.x, acc0.x); acc0.y = fmaf(e0, w.y, acc0.y);
            acc0.z = fmaf(e0, w.z, acc0.z); acc0.w = fmaf(e0, w.w, acc0.w);
            acc1.x = fmaf(e1, w.x, acc1.x); acc1.y = fmaf(e1, w.y, acc1.y);
            acc1.z = fmaf(e1, w.z, acc1.z); acc1.w = fmaf(e1, w.w, acc1.w);
            acc2.x = fmaf(e2, w.x, acc2.x); acc2.y = fmaf(e2, w.y, acc2.y);
            acc2.z = fmaf(e2, w.z, acc2.z); acc2.w = fmaf(e2, w.w, acc2.w);
            acc3.x = fmaf(e3, w.x, acc3.x); acc3.y = fmaf(e3, w.y, acc3.y);
            acc3.z = fmaf(e3, w.z, acc3.z); acc3.w = fmaf(e3, w.w, acc3.w);
        }
    }
    float4 bb = *(const float4*)(b3 + c0);
    float4 r0 = make_float4(fmaxf(acc0.x + bb.x, 0.f), fmaxf(acc0.y + bb.y, 0.f),
                            fmaxf(acc0.z + bb.z, 0.f), fmaxf(acc0.w + bb.w, 0.f));
    float4 r1 = make_float4(fmaxf(acc1.x + bb.x, 0.f), fmaxf(acc1.y + bb.y, 0.f),
                            fmaxf(acc1.z + bb.z, 0.f), fmaxf(acc1.w + bb.w, 0.f));
    float4 r2 = make_float4(fmaxf(acc2.x + bb.x, 0.f), fmaxf(acc2.y + bb.y, 0.f),
                            fmaxf(acc2.z + bb.z, 0.f), fmaxf(acc2.w + bb.w, 0.f));
    float4 r3 = make_float4(fmaxf(acc3.x + bb.x, 0.f), fmaxf(acc3.y + bb.y, 0.f),
                            fmaxf(acc3.z + bb.z, 0.f), fmaxf(acc3.w + bb.w, 0.f));
    float* ob = f3 + ((size_t)(p0 + pbase)) * 256 + c0;
    *(float4*)(ob)           = r0;
    *(float4*)(ob + 256)     = r1;
    *(float4*)(ob + 512)     = r2;
    *(float4*)(ob + 768)     = r3;
}

// ---------------- Kernel C: gather + mean; batch pinned to XCD via blockIdx&7 ----------------
__global__ __launch_bounds__(256) void gather_mean_kernel(const float* __restrict__ f3,
        const int* __restrict__ knn, float* __restrict__ out) {
    int wave = threadIdx.x >> 6, lane = threadIdx.x & 63;
    int b  = blockIdx.x & 7;
    int qg = blockIdx.x >> 3;          // 0..511
    int q  = b * NPTS + qg * 4 + wave;
    const int* kq = knn + (size_t)q * KNN_K;
    const float4* fb = (const float4*)(f3 + (size_t)b * NPTS * 256);
    float4 acc = make_float4(0.f, 0.f, 0.f, 0.f);
#pragma unroll
    for (int k = 0; k < KNN_K; ++k) {
        int j = kq[k];
        float4 v2 = fb[(size_t)j * 64 + lane];
        acc.x += v2.x; acc.y += v2.y; acc.z += v2.z; acc.w += v2.w;
    }
    f32x4 r;
    r.x = acc.x * 0.03125f; r.y = acc.y * 0.03125f;
    r.z = acc.z * 0.03125f; r.w = acc.w * 0.03125f;
    __builtin_nontemporal_store(r, (f32x4*)(out + (size_t)q * 256 + lane * 4));
}

extern "C" void kernel_launch(void* const* d_in, const int* in_sizes, int n_in,
                              void* d_out, int out_size, void* d_ws, size_t ws_size,
                              hipStream_t stream) {
    const float* pts = (const float*)d_in[0];
    const float* W1  = (const float*)d_in[1];
    const float* b1  = (const float*)d_in[2];
    const float* W2  = (const float*)d_in[3];
    const float* b2  = (const float*)d_in[4];
    const float* W3  = (const float*)d_in[5];
    const float* b3  = (const float*)d_in[6];
    float* out = (float*)d_out;
    char* ws = (char*)d_ws;
    int*   knn = (int*)ws;                               // 2 MB
    float* f3  = (float*)(ws + ((size_t)2 << 20));       // 16.8 MB

    hipLaunchKernelGGL(knn_kernel,         dim3(2048), dim3(512), 0, stream, pts, knn);
    hipLaunchKernelGGL(mlp123_kernel,      dim3(1024), dim3(256), 0, stream,
                       pts, W1, b1, W2, b2, W3, b3, f3);
    hipLaunchKernelGGL(gather_mean_kernel, dim3(4096), dim3(256), 0, stream, f3, knn, out);
}